// Round 10
// baseline (758.918 us; speedup 1.0000x reference)
//
#include <hip/hip_runtime.h>
#include <cstdint>

// ---------------------------------------------------------------------------
// GCN: 3x GCNConv(+ELU) + linear head.
// Build (round-5 proven): hist -> scan -> LDS-tile scatter -> sort_deg ->
// sort_scatter (per-node CSR, norm fused). No quarter ordering materialized.
// Aggregation:
//  - F=16 passes: 2 launches x 2 src-quarters, INLINE SKIP of out-of-window
//    edges. Launch boundary = grid-wide phase lock -> every resident block
//    gathers from the same 3.2MB xw slice (fits 4MB per-XCD L2). perm is
//    streamed non-temporally to protect the slice.
//  - F=32 pass: unphased register-accumulator gather (phasing loses to
//    out-RMW + perm restream arithmetic).
// A(XW)=(AX)W associativity: gather passes run at F=16,16,32.
// ---------------------------------------------------------------------------

typedef float __attribute__((ext_vector_type(4))) f4v;

__device__ inline int2 ldnt2(const int2* p) {
    long long v = __builtin_nontemporal_load((const long long*)p);
    int2 r;
    r.x = (int)(unsigned)(v & 0xFFFFFFFFLL);
    r.y = (int)(unsigned)((unsigned long long)v >> 32);
    return r;
}
__device__ inline float4 ldnt4(const float4* p) {
    f4v v = __builtin_nontemporal_load((const f4v*)p);
    float4 r;
    r.x = v.x; r.y = v.y; r.z = v.z; r.w = v.w;
    return r;
}

// ---- Pass A: per-bucket edge counts. bucket = dst >> 8.
__global__ void __launch_bounds__(256) bucket_hist(const int* __restrict__ dst,
                                                   int* __restrict__ bcnt,
                                                   int E, int nbuck, int chunk) {
    __shared__ int h[512];
    for (int i = threadIdx.x; i < 512; i += 256) h[i] = 0;
    __syncthreads();
    int c0 = blockIdx.x * chunk;
    int c1 = min(E, c0 + chunk);
    for (int i = c0 + threadIdx.x; i < c1; i += 256)
        atomicAdd(&h[((unsigned)dst[i]) >> 8], 1);
    __syncthreads();
    for (int i = threadIdx.x; i < nbuck; i += 256)
        if (h[i]) atomicAdd(&bcnt[i], h[i]);
}

// ---- scan of bucket counts -> boff[nbuck+1], global cursors.
__global__ void __launch_bounds__(512) bucket_scan(const int* __restrict__ bcnt,
                                                   int* __restrict__ boff,
                                                   int* __restrict__ gcur,
                                                   int nbuck) {
    __shared__ int part[512];
    int t = threadIdx.x;
    part[t] = (t < nbuck) ? bcnt[t] : 0;
    __syncthreads();
    for (int off = 1; off < 512; off <<= 1) {
        int v = part[t];
        int a = (t >= off) ? part[t - off] : 0;
        __syncthreads();
        part[t] = v + a;
        __syncthreads();
    }
    if (t < nbuck) {
        int excl = (t > 0) ? part[t - 1] : 0;
        boff[t] = excl;
        gcur[t] = excl;
        if (t == nbuck - 1) boff[nbuck] = part[t];  // == E
    }
}

// ---- Pass C: LDS-reorder scatter. TILE=4096 edges/block.
__global__ void __launch_bounds__(256) bucket_scatter(const int* __restrict__ src,
                                                      const int* __restrict__ dst,
                                                      const float* __restrict__ w,
                                                      int* __restrict__ gcur,
                                                      int2* __restrict__ bedge,
                                                      int E) {
    constexpr int TILE = 4096;
    __shared__ int h[512];
    __shared__ int lcnt[512];
    __shared__ int lofs[512];
    __shared__ int gb[512];
    __shared__ int part[256];
    __shared__ int2 sedge[TILE];
    __shared__ unsigned short sbuck[TILE];

    int t = threadIdx.x;
    int c0 = blockIdx.x * TILE;
    int mtile = min(TILE, E - c0);

    for (int i = t; i < 512; i += 256) { h[i] = 0; lcnt[i] = 0; }
    __syncthreads();

    int  my_dst[16];
    int  my_src[16];
    float my_w[16];
#pragma unroll
    for (int k = 0; k < 4; ++k) {
        int e0 = c0 + (t + k * 256) * 4;
        if (e0 + 4 <= E) {
            int4 d4 = *(const int4*)(dst + e0);
            int4 s4 = *(const int4*)(src + e0);
            float4 w4 = *(const float4*)(w + e0);
            my_dst[k*4+0]=d4.x; my_dst[k*4+1]=d4.y; my_dst[k*4+2]=d4.z; my_dst[k*4+3]=d4.w;
            my_src[k*4+0]=s4.x; my_src[k*4+1]=s4.y; my_src[k*4+2]=s4.z; my_src[k*4+3]=s4.w;
            my_w[k*4+0]=w4.x;  my_w[k*4+1]=w4.y;  my_w[k*4+2]=w4.z;  my_w[k*4+3]=w4.w;
        } else {
#pragma unroll
            for (int j = 0; j < 4; ++j) {
                int e = e0 + j;
                bool ok = e < E;
                my_dst[k*4+j] = ok ? dst[e] : -1;
                my_src[k*4+j] = ok ? src[e] : 0;
                my_w[k*4+j]   = ok ? w[e] : 0.f;
            }
        }
    }
#pragma unroll
    for (int j = 0; j < 16; ++j)
        if (my_dst[j] >= 0) atomicAdd(&h[((unsigned)my_dst[j]) >> 8], 1);
    __syncthreads();

    int a0 = h[2 * t], a1 = h[2 * t + 1];
    int s = a0 + a1;
    part[t] = s;
    __syncthreads();
    for (int off = 1; off < 256; off <<= 1) {
        int v = part[t];
        int a = (t >= off) ? part[t - off] : 0;
        __syncthreads();
        part[t] = v + a;
        __syncthreads();
    }
    int excl = part[t] - s;
    lofs[2 * t] = excl;
    lofs[2 * t + 1] = excl + a0;
    if (a0) gb[2 * t] = atomicAdd(&gcur[2 * t], a0) - excl;
    if (a1) gb[2 * t + 1] = atomicAdd(&gcur[2 * t + 1], a1) - (excl + a0);
    __syncthreads();

#pragma unroll
    for (int j = 0; j < 16; ++j) {
        int d = my_dst[j];
        if (d < 0) continue;
        unsigned ud = (unsigned)d;
        int b = ud >> 8;
        int p = lofs[b] + atomicAdd(&lcnt[b], 1);
        int2 e;
        e.x = (int)(((ud & 255u) << 24) | (unsigned)my_src[j]);
        e.y = __float_as_int(my_w[j]);
        sedge[p] = e;
        sbuck[p] = (unsigned short)b;
    }
    __syncthreads();

    for (int i = t; i < mtile; i += 256) {
        int b = sbuck[i];
        bedge[gb[b] + i] = sedge[i];
    }
}

// ---- Pass D: per-bucket deg -> row_ptr, dinv.
__global__ void __launch_bounds__(256) sort_deg(const int* __restrict__ boff,
                                                const int2* __restrict__ bedge,
                                                int* __restrict__ row_ptr,
                                                float* __restrict__ dinv,
                                                int N, int E) {
    __shared__ int cnt[256];
    __shared__ float deg[256];
    __shared__ int part[256];
    int b = blockIdx.x;
    int base = boff[b];
    int m = boff[b + 1] - base;
    int t = threadIdx.x;
    cnt[t] = 0;
    deg[t] = 0.f;
    __syncthreads();
    for (int i = t; i < m; i += 256) {
        int2 e = bedge[base + i];
        unsigned l = ((unsigned)e.x) >> 24;
        atomicAdd(&cnt[l], 1);
        atomicAdd(&deg[l], __int_as_float(e.y));
    }
    __syncthreads();
    part[t] = cnt[t];
    __syncthreads();
    for (int off = 1; off < 256; off <<= 1) {
        int v = part[t];
        int a = (t >= off) ? part[t - off] : 0;
        __syncthreads();
        part[t] = v + a;
        __syncthreads();
    }
    int excl = part[t] - cnt[t];
    int node = b * 256 + t;
    if (node < N) {
        row_ptr[node] = base + excl;
        dinv[node] = rsqrtf(deg[t] + 1.0f);
    }
    if (b == 0 && t == 0) row_ptr[N] = E;
}

// ---- Pass E: bedge -> perm (CSR order) with fused norm.
__global__ void __launch_bounds__(256) sort_scatter(const int* __restrict__ boff,
                                                    const int2* __restrict__ bedge,
                                                    const int* __restrict__ row_ptr,
                                                    const float* __restrict__ dinv,
                                                    int2* __restrict__ perm, int N) {
    __shared__ int cur[256];
    __shared__ float sdinv[256];
    int b = blockIdx.x;
    int base = boff[b];
    int m = boff[b + 1] - base;
    int t = threadIdx.x;
    int node = b * 256 + t;
    cur[t] = (node < N) ? row_ptr[node] : 0;
    sdinv[t] = (node < N) ? dinv[node] : 0.f;
    __syncthreads();
    for (int i = t; i < m; i += 256) {
        int2 e = bedge[base + i];
        unsigned ux = (unsigned)e.x;
        unsigned l = ux >> 24;
        int sidx = (int)(ux & 0xFFFFFFu);
        float nm = dinv[sidx] * __int_as_float(e.y) * sdinv[l];
        int pos = atomicAdd(&cur[l], 1);
        int2 p;
        p.x = sidx;
        p.y = __float_as_int(nm);
        perm[pos] = p;
    }
}

// x[N,256] @ W[256,16] -> xw[N,16].
__global__ void __launch_bounds__(256) gemm_x16(const float* __restrict__ x,
                                                const float* __restrict__ W,
                                                float* __restrict__ xw, int N) {
    __shared__ float Ws[256 * 16];
    for (int i = threadIdx.x; i < 256 * 16; i += 256) Ws[i] = W[i];
    __syncthreads();
    int c = threadIdx.x & 15;
    int rl = threadIdx.x >> 4;
    int r = blockIdx.x * 16 + rl;
    if (r >= N) return;
    const float4* x4 = (const float4*)(x + (size_t)r * 256);
    float acc = 0.f;
#pragma unroll 8
    for (int k4 = 0; k4 < 64; ++k4) {
        float4 v = ldnt4(x4 + k4);
        const float* wr = &Ws[k4 * 64 + c];
        acc += v.x * wr[0] + v.y * wr[16] + v.z * wr[32] + v.w * wr[48];
    }
    xw[(size_t)r * 16 + c] = acc;
}

// in[N,K] @ W[K,F] + bias -> out[N,F], optional ELU on output.
template <int K, int F, bool OUT_ELU>
__global__ void __launch_bounds__(256) gemm_small(const float* __restrict__ in,
                                                  const float* __restrict__ W,
                                                  const float* __restrict__ bias,
                                                  float* __restrict__ out, int N) {
    constexpr int ROWS = 256 / F;
    __shared__ float Ws[K * F];
    __shared__ float Is[ROWS * K];
    for (int i = threadIdx.x; i < K * F; i += 256) Ws[i] = W[i];
    int r0 = blockIdx.x * ROWS;
    for (int i = threadIdx.x; i < ROWS * K; i += 256)
        Is[i] = in[(size_t)r0 * K + i];
    __syncthreads();
    int c = threadIdx.x % F;
    int rl = threadIdx.x / F;
    float acc = bias[c];
#pragma unroll
    for (int k = 0; k < K; ++k) acc += Is[rl * K + k] * Ws[k * F + c];
    if (OUT_ELU) acc = acc > 0.f ? acc : expm1f(acc);
    out[(size_t)(r0 + rl) * F + c] = acc;
}

// ---- F=16 phased gather with inline skip. One launch per 2-quarter window.
// flags: bit0 = init (self-loop [+bias]), bit1 = final (apply ELU if ELU).
template <bool ELU>
__global__ void __launch_bounds__(256) agg_skip16(const int* __restrict__ row_ptr,
                                                  const int2* __restrict__ perm,
                                                  const float* __restrict__ xw,
                                                  const float* __restrict__ dinv,
                                                  const float* __restrict__ bias,
                                                  float* __restrict__ out,
                                                  int N, int slo, int span, int flags) {
    constexpr int G = 4;               // lanes per node (16 floats / float4)
    int node = blockIdx.x * 64 + threadIdx.x / G;
    int q = threadIdx.x % G;
    if (node >= N) return;
    const float4* xw4 = (const float4*)xw;
    float4* out4 = (float4*)out;
    float4 a0, a1, a2, a3;
    if (flags & 1) {
        float di = dinv[node];
        float d2 = di * di;
        float4 s = xw4[(size_t)node * G + q];
        a0.x = d2 * s.x; a0.y = d2 * s.y; a0.z = d2 * s.z; a0.w = d2 * s.w;
        if (bias) {
            float4 b4 = ((const float4*)bias)[q];
            a0.x += b4.x; a0.y += b4.y; a0.z += b4.z; a0.w += b4.w;
        }
    } else {
        a0 = out4[(size_t)node * G + q];
    }
    a1 = make_float4(0.f, 0.f, 0.f, 0.f);
    a2 = a1; a3 = a1;
    int j = row_ptr[node];
    int je = row_ptr[node + 1];
    unsigned uspan = (unsigned)span;
    for (; j + 3 < je; j += 4) {
        int2 p0 = ldnt2(perm + j);
        int2 p1 = ldnt2(perm + j + 1);
        int2 p2 = ldnt2(perm + j + 2);
        int2 p3 = ldnt2(perm + j + 3);
        if ((unsigned)(p0.x - slo) < uspan) {
            float4 v = xw4[(size_t)p0.x * G + q];
            float n = __int_as_float(p0.y);
            a0.x += n * v.x; a0.y += n * v.y; a0.z += n * v.z; a0.w += n * v.w;
        }
        if ((unsigned)(p1.x - slo) < uspan) {
            float4 v = xw4[(size_t)p1.x * G + q];
            float n = __int_as_float(p1.y);
            a1.x += n * v.x; a1.y += n * v.y; a1.z += n * v.z; a1.w += n * v.w;
        }
        if ((unsigned)(p2.x - slo) < uspan) {
            float4 v = xw4[(size_t)p2.x * G + q];
            float n = __int_as_float(p2.y);
            a2.x += n * v.x; a2.y += n * v.y; a2.z += n * v.z; a2.w += n * v.w;
        }
        if ((unsigned)(p3.x - slo) < uspan) {
            float4 v = xw4[(size_t)p3.x * G + q];
            float n = __int_as_float(p3.y);
            a3.x += n * v.x; a3.y += n * v.y; a3.z += n * v.z; a3.w += n * v.w;
        }
    }
    for (; j < je; ++j) {
        int2 p0 = ldnt2(perm + j);
        if ((unsigned)(p0.x - slo) < uspan) {
            float4 v = xw4[(size_t)p0.x * G + q];
            float n = __int_as_float(p0.y);
            a0.x += n * v.x; a0.y += n * v.y; a0.z += n * v.z; a0.w += n * v.w;
        }
    }
    float4 r;
    r.x = (a0.x + a1.x) + (a2.x + a3.x);
    r.y = (a0.y + a1.y) + (a2.y + a3.y);
    r.z = (a0.z + a1.z) + (a2.z + a3.z);
    r.w = (a0.w + a1.w) + (a2.w + a3.w);
    if (ELU && (flags & 2)) {
        r.x = r.x > 0.f ? r.x : expm1f(r.x);
        r.y = r.y > 0.f ? r.y : expm1f(r.y);
        r.z = r.z > 0.f ? r.z : expm1f(r.z);
        r.w = r.w > 0.f ? r.w : expm1f(r.w);
    }
    out4[(size_t)node * G + q] = r;
}

// ---- F=32 unphased register-accumulator gather (round-5 proven).
template <int F, bool BIAS_ELU>
__global__ void __launch_bounds__(256) agg4(const int* __restrict__ row_ptr,
                                            const int2* __restrict__ perm,
                                            const float* __restrict__ xw,
                                            const float* __restrict__ dinv,
                                            const float* __restrict__ bias,
                                            float* __restrict__ out, int N) {
    constexpr int G = F / 4;
    constexpr int NPB = 256 / G;
    int node = blockIdx.x * NPB + threadIdx.x / G;
    int q = threadIdx.x % G;
    if (node >= N) return;
    const float4* xw4 = (const float4*)xw;
    float di = dinv[node];
    float4 s = xw4[(size_t)node * G + q];
    float d2 = di * di;
    float4 a0 = {d2 * s.x, d2 * s.y, d2 * s.z, d2 * s.w};
    float4 a1 = {0.f, 0.f, 0.f, 0.f};
    float4 a2 = {0.f, 0.f, 0.f, 0.f};
    float4 a3 = {0.f, 0.f, 0.f, 0.f};
    int beg = row_ptr[node];
    int end = row_ptr[node + 1];
    int j = beg;
    for (; j + 3 < end; j += 4) {
        int2 p0 = perm[j];
        int2 p1 = perm[j + 1];
        int2 p2 = perm[j + 2];
        int2 p3 = perm[j + 3];
        float4 v0 = xw4[(size_t)p0.x * G + q];
        float4 v1 = xw4[(size_t)p1.x * G + q];
        float4 v2 = xw4[(size_t)p2.x * G + q];
        float4 v3 = xw4[(size_t)p3.x * G + q];
        float n0 = __int_as_float(p0.y);
        float n1 = __int_as_float(p1.y);
        float n2 = __int_as_float(p2.y);
        float n3 = __int_as_float(p3.y);
        a0.x += n0 * v0.x; a0.y += n0 * v0.y; a0.z += n0 * v0.z; a0.w += n0 * v0.w;
        a1.x += n1 * v1.x; a1.y += n1 * v1.y; a1.z += n1 * v1.z; a1.w += n1 * v1.w;
        a2.x += n2 * v2.x; a2.y += n2 * v2.y; a2.z += n2 * v2.z; a2.w += n2 * v2.w;
        a3.x += n3 * v3.x; a3.y += n3 * v3.y; a3.z += n3 * v3.z; a3.w += n3 * v3.w;
    }
    for (; j < end; ++j) {
        int2 p0 = perm[j];
        float4 v0 = xw4[(size_t)p0.x * G + q];
        float n0 = __int_as_float(p0.y);
        a0.x += n0 * v0.x; a0.y += n0 * v0.y; a0.z += n0 * v0.z; a0.w += n0 * v0.w;
    }
    float4 r;
    r.x = (a0.x + a1.x) + (a2.x + a3.x);
    r.y = (a0.y + a1.y) + (a2.y + a3.y);
    r.z = (a0.z + a1.z) + (a2.z + a3.z);
    r.w = (a0.w + a1.w) + (a2.w + a3.w);
    if (BIAS_ELU) {
        float4 b4 = ((const float4*)bias)[q];
        r.x += b4.x; r.y += b4.y; r.z += b4.z; r.w += b4.w;
        r.x = r.x > 0.f ? r.x : expm1f(r.x);
        r.y = r.y > 0.f ? r.y : expm1f(r.y);
        r.z = r.z > 0.f ? r.z : expm1f(r.z);
        r.w = r.w > 0.f ? r.w : expm1f(r.w);
    }
    ((float4*)out)[(size_t)node * G + q] = r;
}

extern "C" void kernel_launch(void* const* d_in, const int* in_sizes, int n_in,
                              void* d_out, int out_size, void* d_ws, size_t ws_size,
                              hipStream_t stream) {
    const float* x  = (const float*)d_in[0];
    const int*   ei = (const int*)d_in[1];
    const float* w  = (const float*)d_in[2];
    const float* W0 = (const float*)d_in[3];
    const float* b0 = (const float*)d_in[4];
    const float* W1 = (const float*)d_in[5];
    const float* b1 = (const float*)d_in[6];
    const float* W2 = (const float*)d_in[7];
    const float* b2 = (const float*)d_in[8];
    const float* Wm = (const float*)d_in[9];
    const float* bm = (const float*)d_in[10];
    float* out = (float*)d_out;

    const int N = in_sizes[0] / 256;
    const int E = in_sizes[2];
    const int* src = ei;
    const int* dst = ei + E;
    const int nbuck = (N + 255) >> 8;
    const int qs = (N + 3) / 4;            // src-quarter size
    const int half = 2 * qs;               // 2-quarter window

    char* ws = (char*)d_ws;
    size_t off = 0;
    auto alloc = [&](size_t bytes) {
        void* p = ws + off;
        off = (off + bytes + 255) & ~(size_t)255;
        return p;
    };
    float* dinv    = (float*)alloc((size_t)N * 4);
    int*   row_ptr = (int*)alloc(((size_t)N + 1) * 4);
    int*   bcnt    = (int*)alloc(520 * 4);
    int*   boff    = (int*)alloc(520 * 4);
    int*   gcur    = (int*)alloc(520 * 4);
    int2*  bedge   = (int2*)alloc((size_t)E * 8);
    int2*  perm    = (int2*)alloc((size_t)E * 8);
    float* BUF_A   = (float*)alloc((size_t)N * 32 * 4);
    float* BUF_B   = (float*)alloc((size_t)N * 32 * 4);

    hipMemsetAsync(bcnt, 0, 520 * 4, stream);

    const int CH = 8192;
    const int sblk = (E + CH - 1) / CH;

    // ---- build CSR (layer-invariant, round-5 structure)
    bucket_hist<<<sblk, 256, 0, stream>>>(dst, bcnt, E, nbuck, CH);
    bucket_scan<<<1, 512, 0, stream>>>(bcnt, boff, gcur, nbuck);
    bucket_scatter<<<(E + 4095) / 4096, 256, 0, stream>>>(src, dst, w, gcur, bedge, E);
    sort_deg<<<nbuck, 256, 0, stream>>>(boff, bedge, row_ptr, dinv, N, E);
    sort_scatter<<<nbuck, 256, 0, stream>>>(boff, bedge, row_ptr, dinv, perm, N);

    const int AGB16 = (N + 63) / 64;

    // ---- layer 0: XW = x@W0 ; h1 = elu(A.XW + b0)   [2 phased launches]
    gemm_x16<<<(N + 15) / 16, 256, 0, stream>>>(x, W0, BUF_A, N);
    agg_skip16<true><<<AGB16, 256, 0, stream>>>(row_ptr, perm, BUF_A, dinv, b0, BUF_B, N, 0, half, 1);
    agg_skip16<true><<<AGB16, 256, 0, stream>>>(row_ptr, perm, BUF_A, dinv, b0, BUF_B, N, half, half, 2);

    // ---- layer 1: AG1 = A.h1 ; h2 = elu(AG1@W1 + b1)   [2 phased launches]
    agg_skip16<false><<<AGB16, 256, 0, stream>>>(row_ptr, perm, BUF_B, dinv, nullptr, BUF_A, N, 0, half, 1);
    agg_skip16<false><<<AGB16, 256, 0, stream>>>(row_ptr, perm, BUF_B, dinv, nullptr, BUF_A, N, half, half, 2);
    gemm_small<16, 32, true><<<(N + 7) / 8, 256, 0, stream>>>(BUF_A, W1, b1, BUF_B, N);

    // ---- layer 2: AG2 = A.h2 (unphased) ; h3 = elu(AG2@W2 + b2)
    agg4<32, false><<<(N + 31) / 32, 256, 0, stream>>>(row_ptr, perm, BUF_B, dinv, nullptr, BUF_A, N);
    gemm_small<32, 32, true><<<(N + 7) / 8, 256, 0, stream>>>(BUF_A, W2, b2, BUF_B, N);

    // ---- head: out = h3@Wm + bm
    gemm_small<32, 16, false><<<(N + 15) / 16, 256, 0, stream>>>(BUF_B, Wm, bm, out, N);
}